// Round 1
// baseline (1365.288 us; speedup 1.0000x reference)
//
#include <hip/hip_runtime.h>

#define NB 8192
#define ND 512
#define QB 32
#define KB 64
#define NT (NB / KB)

typedef unsigned short u16;
typedef unsigned int u32;
typedef __attribute__((ext_vector_type(8))) short bf16x8;
typedef __attribute__((ext_vector_type(4))) float f32x4;

__device__ inline u16 f2bf(float f) {
  u32 u = __float_as_uint(f);
  return (u16)((u + 0x7fffu + ((u >> 16) & 1u)) >> 16);
}

// ---------------- prep: row rnorms + f32 -> bf16 ----------------
__global__ __launch_bounds__(256) void prep_kernel(const float* __restrict__ x,
                                                   float* __restrict__ rnorm,
                                                   u16* __restrict__ xbf) {
  int row = blockIdx.x * 4 + (threadIdx.x >> 6);
  int lane = threadIdx.x & 63;
  const float4* xr = reinterpret_cast<const float4*>(x + (size_t)row * ND);
  float4 a = xr[lane];
  float4 b = xr[64 + lane];
  float ss = a.x * a.x + a.y * a.y + a.z * a.z + a.w * a.w +
             b.x * b.x + b.y * b.y + b.z * b.z + b.w * b.w;
  ss += __shfl_xor(ss, 1);  ss += __shfl_xor(ss, 2);  ss += __shfl_xor(ss, 4);
  ss += __shfl_xor(ss, 8);  ss += __shfl_xor(ss, 16); ss += __shfl_xor(ss, 32);
  float rn = 1.0f / fmaxf(sqrtf(ss), 1e-12f);
  if (lane == 0) rnorm[row] = rn;

  u16* dst = xbf + (size_t)row * ND;
  ushort4 ua = {f2bf(a.x), f2bf(a.y), f2bf(a.z), f2bf(a.w)};
  ushort4 ub = {f2bf(b.x), f2bf(b.y), f2bf(b.z), f2bf(b.w)};
  reinterpret_cast<ushort4*>(dst)[lane] = ua;
  reinterpret_cast<ushort4*>(dst)[64 + lane] = ub;
}

// ---------------- fused attention ----------------
// grid 256 (one 32-row q-block per WG), 512 threads (8 waves)
__global__ __launch_bounds__(512, 2) void attn_kernel(const u16* __restrict__ xbf,
                                                      const float* __restrict__ rnorm,
                                                      float* __restrict__ out) {
  __shared__ u16 Ks[KB * ND];   // [kv][d], xor-swizzled by kv
  __shared__ u16 Vt[ND * KB];   // [d][kv], xor-swizzled by d
  __shared__ u16 Pl[QB * KB];   // [q][kv], xor-swizzled by q
  __shared__ float rKs[KB];
  __shared__ float Zpart[8 * 16];
  __shared__ float Zfin[QB];

  const int tid = threadIdx.x;
  const int w = tid >> 6;
  const int l = tid & 63;
  const int qb = blockIdx.x;

  // ---- stage Q rows (qb*32 .. +32) into Ks region temporarily
  {
    int qr = tid >> 4;
    int dc = (tid & 15) * 32;
    const uint4* src = reinterpret_cast<const uint4*>(xbf + ((size_t)(qb * QB + qr)) * ND + dc);
#pragma unroll
    for (int j = 0; j < 4; ++j) {
      uint4 v = src[j];
      int elem = qr * ND + dc + j * 8;
      *(uint4*)((char*)Ks + ((elem * 2) ^ ((qr & 7) << 4))) = v;
    }
  }
  __syncthreads();

  const int qt = w & 1;             // q sub-tile (16 rows) for phase1 & 2
  const int kt = w >> 1;            // phase1 kv sub-tile 0..3
  const int dblk = (w >> 1) * 128;  // phase2 d block

  // ---- Q fragments -> registers (A-operand, 16 k-steps)
  bf16x8 qf[16];
  {
    int qrow = qt * 16 + (l & 15);
#pragma unroll
    for (int ks = 0; ks < 16; ++ks) {
      int elem = qrow * ND + ks * 32 + (l >> 4) * 8;
      qf[ks] = *(const bf16x8*)((const char*)Ks + ((elem * 2) ^ ((qrow & 7) << 4)));
    }
  }
  float rnq[4];
#pragma unroll
  for (int r = 0; r < 4; ++r) rnq[r] = rnorm[qb * QB + qt * 16 + (l >> 4) * 4 + r];

  // ---- preload tile 0
  const int s_kvr = tid >> 3;        // 0..63 tile-local kv row
  const int s_dc = (tid & 7) * 64;   // 64 bf16 per thread
  const int half = (tid >> 3) & 1;   // kv parity
  uint4 sreg[8];
  float srn;
  {
    const uint4* src = reinterpret_cast<const uint4*>(xbf + ((size_t)s_kvr) * ND + s_dc);
#pragma unroll
    for (int j = 0; j < 8; ++j) sreg[j] = src[j];
    srn = rnorm[l];
  }

  f32x4 oacc[8];
#pragma unroll
  for (int i = 0; i < 8; ++i) oacc[i] = (f32x4){0.f, 0.f, 0.f, 0.f};
  float zacc[4] = {0.f, 0.f, 0.f, 0.f};

  for (int t = 0; t < NT; ++t) {
    __syncthreads();  // (A) LDS free for restaging

    // Ks row-major writes (b128, swizzled)
#pragma unroll
    for (int j = 0; j < 8; ++j) {
      int elem = s_kvr * ND + s_dc + j * 8;
      *(uint4*)((char*)Ks + ((elem * 2) ^ ((s_kvr & 7) << 4))) = sreg[j];
    }
    // Vt transposed writes via lane-pairing (kv, kv^1 share one u32)
    {
      int kvp = s_kvr & ~1;
#pragma unroll
      for (int j = 0; j < 8; ++j) {
        bool mine = ((j < 4) == (half == 0));
#pragma unroll
        for (int k = 0; k < 4; ++k) {
          int kk = (k + (tid & 3)) & 3;  // rotate to spread banks
          u32 wv = ((const u32*)&sreg[j])[kk];
          u32 pv = __shfl_xor(wv, 8);
          if (mine) {
            u32 w0, w1;
            if (half == 0) {
              w0 = (wv & 0xffffu) | (pv << 16);
              w1 = (wv >> 16) | (pv & 0xffff0000u);
            } else {
              w0 = (pv & 0xffffu) | (wv << 16);
              w1 = (pv >> 16) | (wv & 0xffff0000u);
            }
            int d0 = s_dc + j * 8 + kk * 2;
            *(u32*)((char*)Vt + (((d0 * KB + kvp) * 2) ^ ((d0 & 7) << 4))) = w0;
            int d1 = d0 + 1;
            *(u32*)((char*)Vt + (((d1 * KB + kvp) * 2) ^ ((d1 & 7) << 4))) = w1;
          }
        }
      }
    }
    if (tid < KB) rKs[tid] = srn;

    // preload tile t+1 (hidden under phase1+phase2)
    if (t + 1 < NT) {
      const uint4* src =
          reinterpret_cast<const uint4*>(xbf + ((size_t)((t + 1) * KB + s_kvr)) * ND + s_dc);
#pragma unroll
      for (int j = 0; j < 8; ++j) sreg[j] = src[j];
      srn = rnorm[(t + 1) * KB + l];
    }
    __syncthreads();  // (B) staging visible

    // ---- phase 1: S(16x16) = Q_qt · K_kt^T over 512
    f32x4 acc = {0.f, 0.f, 0.f, 0.f};
    {
      int kvrow = kt * 16 + (l & 15);
#pragma unroll
      for (int ks = 0; ks < 16; ++ks) {
        int elem = kvrow * ND + ks * 32 + (l >> 4) * 8;
        bf16x8 bf = *(const bf16x8*)((const char*)Ks + ((elem * 2) ^ ((kvrow & 7) << 4)));
        acc = __builtin_amdgcn_mfma_f32_16x16x32_bf16(qf[ks], bf, acc, 0, 0, 0);
      }
    }
    // scale to cosine, exp, accumulate Z, write P (bf16)
    {
      float rnk = rKs[kt * 16 + (l & 15)];
#pragma unroll
      for (int r = 0; r < 4; ++r) {
        float p = __expf(acc[r] * rnq[r] * rnk);
        zacc[r] += p;
        int q_l = qt * 16 + (l >> 4) * 4 + r;
        int elem = q_l * KB + kt * 16 + (l & 15);
        *(u16*)((char*)Pl + ((elem * 2) ^ ((q_l & 7) << 4))) = f2bf(p);
      }
    }
    __syncthreads();  // (C) P ready

    // ---- phase 2: O += P · V
    {
      bf16x8 pa[2];
      int qrow = qt * 16 + (l & 15);
#pragma unroll
      for (int ks = 0; ks < 2; ++ks) {
        int elem = qrow * KB + ks * 32 + (l >> 4) * 8;
        pa[ks] = *(const bf16x8*)((const char*)Pl + ((elem * 2) ^ ((qrow & 7) << 4)));
      }
#pragma unroll
      for (int dt = 0; dt < 8; ++dt) {
        int drow = dblk + dt * 16 + (l & 15);
#pragma unroll
        for (int ks = 0; ks < 2; ++ks) {
          int elem = drow * KB + ks * 32 + (l >> 4) * 8;
          bf16x8 vf = *(const bf16x8*)((const char*)Vt + ((elem * 2) ^ ((drow & 7) << 4)));
          oacc[dt] = __builtin_amdgcn_mfma_f32_16x16x32_bf16(pa[ks], vf, oacc[dt], 0, 0, 0);
        }
      }
    }
  }

  // ---- Z reduction: sum over 16 lanes (cols), then over the 4 kt-waves
  float z[4];
#pragma unroll
  for (int r = 0; r < 4; ++r) {
    float s = zacc[r];
    s += __shfl_xor(s, 1); s += __shfl_xor(s, 2);
    s += __shfl_xor(s, 4); s += __shfl_xor(s, 8);
    z[r] = s;
  }
  if ((l & 15) == 0) {
#pragma unroll
    for (int r = 0; r < 4; ++r) Zpart[w * 16 + (l >> 4) * 4 + r] = z[r];
  }
  __syncthreads();
  if (tid < QB) {
    int qt_ = tid >> 4;
    float s = 0.f;
#pragma unroll
    for (int i = 0; i < 4; ++i) s += Zpart[(qt_ + 2 * i) * 16 + (tid & 15)];
    Zfin[tid] = s;
  }
  __syncthreads();

  // ---- normalize + store f32
#pragma unroll
  for (int r = 0; r < 4; ++r) {
    int q_l = qt * 16 + (l >> 4) * 4 + r;
    float zin = 1.0f / Zfin[q_l];
    size_t rowoff = ((size_t)(qb * QB + q_l)) * ND;
#pragma unroll
    for (int dt = 0; dt < 8; ++dt) {
      out[rowoff + dblk + dt * 16 + (l & 15)] = oacc[dt][r] * zin;
    }
  }
}

extern "C" void kernel_launch(void* const* d_in, const int* in_sizes, int n_in,
                              void* d_out, int out_size, void* d_ws, size_t ws_size,
                              hipStream_t stream) {
  const float* x = (const float*)d_in[0];
  float* outp = (float*)d_out;
  float* rnorm = (float*)d_ws;
  u16* xbf = (u16*)((char*)d_ws + (size_t)NB * sizeof(float));

  prep_kernel<<<NB / 4, 256, 0, stream>>>(x, rnorm, xbf);
  attn_kernel<<<NB / QB, 512, 0, stream>>>(xbf, rnorm, outp);
}